// Round 1
// baseline (819.916 us; speedup 1.0000x reference)
//
#include <hip/hip_runtime.h>

// Problem constants (match reference: B=4096, D=128, H=256, C=64, fp32)
constexpr int B = 4096;
constexpr int D = 128;
constexpr int H = 256;
constexpr int C = 64;

// One block per batch sample b.
//   h  = relu(x[b] @ w1[b] + b1[b])   : [1,D]@[D,H] -> [H]
//   out= h @ w2[b] + b2[b]            : [1,H]@[H,C] -> [C]
// All w1/w2 traffic is float4 (16 B/lane) fully coalesced; each element read once.
__global__ __launch_bounds__(256) void TargetNetwork_20985210208628_kernel(
    const float* __restrict__ x,
    const float* __restrict__ w1,
    const float* __restrict__ b1,
    const float* __restrict__ w2,
    const float* __restrict__ b2,
    float* __restrict__ out)
{
    const int b    = blockIdx.x;
    const int t    = threadIdx.x;
    const int wave = t >> 6;   // 0..3
    const int lane = t & 63;   // 0..63

    __shared__ float x_s[D];          // 512 B
    __shared__ float part1[4][H];     // 4 KB
    __shared__ float h_s[H];          // 1 KB
    __shared__ float part2[16][C];    // 4 KB

    // ---- stage x[b] into LDS ----
    if (t < D) x_s[t] = x[(size_t)b * D + t];
    __syncthreads();

    // ---- phase 1: h = relu(x @ w1 + b1) ----
    // wave covers d in [wave*32, wave*32+32); lane covers columns [4*lane, 4*lane+4)
    {
        const float* w1b = w1 + (size_t)b * D * H;
        const int col = lane * 4;
        float a0 = 0.f, a1 = 0.f, a2 = 0.f, a3 = 0.f;
        #pragma unroll 8
        for (int k = 0; k < 32; ++k) {
            const int d = wave * 32 + k;
            const float4 wv = *reinterpret_cast<const float4*>(w1b + (size_t)d * H + col);
            const float xs = x_s[d];  // wave-uniform -> LDS broadcast
            a0 += xs * wv.x; a1 += xs * wv.y; a2 += xs * wv.z; a3 += xs * wv.w;
        }
        *reinterpret_cast<float4*>(&part1[wave][col]) = make_float4(a0, a1, a2, a3);
    }
    __syncthreads();

    // reduce 4 wave-partials per h-column, add bias, relu
    {
        const float hsum = part1[0][t] + part1[1][t] + part1[2][t] + part1[3][t]
                         + b1[(size_t)b * H + t];
        h_s[t] = hsum > 0.f ? hsum : 0.f;
    }
    __syncthreads();

    // ---- phase 2: out = h @ w2 + b2 ----
    // group g = t/16 covers j in [16g, 16g+16); i = t%16 covers columns [4i, 4i+4)
    {
        const float* w2b = w2 + (size_t)b * H * C;
        const int g = t >> 4;     // 0..15
        const int i = t & 15;     // 0..15
        const int c4 = i * 4;
        float o0 = 0.f, o1 = 0.f, o2 = 0.f, o3 = 0.f;
        #pragma unroll 8
        for (int k = 0; k < 16; ++k) {
            const int j = g * 16 + k;
            const float4 wv = *reinterpret_cast<const float4*>(w2b + (size_t)j * C + c4);
            const float hj = h_s[j];
            o0 += hj * wv.x; o1 += hj * wv.y; o2 += hj * wv.z; o3 += hj * wv.w;
        }
        *reinterpret_cast<float4*>(&part2[g][c4]) = make_float4(o0, o1, o2, o3);
    }
    __syncthreads();

    // reduce 16 group-partials per c-column, add bias, store
    if (t < C) {
        float s = b2[(size_t)b * C + t];
        #pragma unroll
        for (int g2 = 0; g2 < 16; ++g2) s += part2[g2][t];
        out[(size_t)b * C + t] = s;
    }
}

extern "C" void kernel_launch(void* const* d_in, const int* in_sizes, int n_in,
                              void* d_out, int out_size, void* d_ws, size_t ws_size,
                              hipStream_t stream) {
    const float* x  = (const float*)d_in[0];
    const float* w1 = (const float*)d_in[1];
    const float* b1 = (const float*)d_in[2];
    const float* w2 = (const float*)d_in[3];
    const float* b2 = (const float*)d_in[4];
    float* out = (float*)d_out;

    TargetNetwork_20985210208628_kernel<<<B, 256, 0, stream>>>(x, w1, b1, w2, b2, out);
}

// Round 2
// 792.787 us; speedup vs baseline: 1.0342x; 1.0342x over previous
//
#include <hip/hip_runtime.h>

// Problem: per-sample 2-layer MLP, B=4096, D=128, H=256, C=64, fp32.
// HBM-bound: 776 MB read / launch, ~120 us floor at 6.5 TB/s.
constexpr int B = 4096;
constexpr int D = 128;
constexpr int H = 256;
constexpr int C = 64;

typedef float f4 __attribute__((ext_vector_type(4)));

// One block (256 thr) per sample. Interleaved row assignment so that at each
// inner step the whole block reads ONE contiguous 4 KB run of the weight
// matrix (DRAM-friendly), instead of 4/16 scattered chunks.
__global__ __launch_bounds__(256) void TargetNetwork_20985210208628_kernel(
    const float* __restrict__ x,
    const float* __restrict__ w1,
    const float* __restrict__ b1,
    const float* __restrict__ w2,
    const float* __restrict__ b2,
    float* __restrict__ out)
{
    const int b    = blockIdx.x;
    const int t    = threadIdx.x;
    const int wave = t >> 6;   // 0..3
    const int lane = t & 63;   // 0..63

    __shared__ float x_s[D];          // 512 B
    __shared__ float part1[4][H];     // 4 KB
    __shared__ float h_s[H];          // 1 KB
    __shared__ float part2[16][C];    // 4 KB

    if (t < D) x_s[t] = x[(size_t)b * D + t];
    __syncthreads();

    // ---- phase 1: h = relu(x @ w1 + b1) ----
    // wave w covers rows d = 4k+w; at step k the block reads rows 4k..4k+3
    // = 4 KB contiguous. Lane covers 4 consecutive h-columns (16 B/lane).
    {
        const float* w1b = w1 + (size_t)b * (D * H);
        const int col = lane * 4;
        f4 acc = {0.f, 0.f, 0.f, 0.f};
        #pragma unroll 8
        for (int k = 0; k < 32; ++k) {
            const int d = (k << 2) + wave;
            const f4 wv = __builtin_nontemporal_load(
                reinterpret_cast<const f4*>(w1b + (size_t)d * H + col));
            acc += x_s[d] * wv;   // x_s[d] wave-uniform -> LDS broadcast
        }
        *reinterpret_cast<f4*>(&part1[wave][col]) = acc;
    }
    __syncthreads();

    // reduce 4 wave-partials per h-column, add bias, relu
    {
        const float hsum = part1[0][t] + part1[1][t] + part1[2][t] + part1[3][t]
                         + b1[(size_t)b * H + t];
        h_s[t] = fmaxf(hsum, 0.f);
    }
    __syncthreads();

    // ---- phase 2: out = h @ w2 + b2 ----
    // group g = t/16 covers rows j = 16k+g; at step k the block reads rows
    // 16k..16k+15 = 4 KB contiguous (each wave a 1 KB contiguous run).
    {
        const float* w2b = w2 + (size_t)b * (H * C);
        const int g  = t >> 4;    // 0..15
        const int i  = t & 15;    // 0..15
        const int c4 = i * 4;
        f4 acc = {0.f, 0.f, 0.f, 0.f};
        #pragma unroll 8
        for (int k = 0; k < 16; ++k) {
            const int j = (k << 4) + g;
            const f4 wv = __builtin_nontemporal_load(
                reinterpret_cast<const f4*>(w2b + (size_t)j * C + c4));
            acc += h_s[j] * wv;   // h_s[j] uniform across the 16-lane group
        }
        *reinterpret_cast<f4*>(&part2[g][c4]) = acc;
    }
    __syncthreads();

    // reduce 16 group-partials per c-column, add bias, store
    if (t < C) {
        float s = b2[(size_t)b * C + t];
        #pragma unroll
        for (int g2 = 0; g2 < 16; ++g2) s += part2[g2][t];
        out[(size_t)b * C + t] = s;
    }
}

extern "C" void kernel_launch(void* const* d_in, const int* in_sizes, int n_in,
                              void* d_out, int out_size, void* d_ws, size_t ws_size,
                              hipStream_t stream) {
    const float* x  = (const float*)d_in[0];
    const float* w1 = (const float*)d_in[1];
    const float* b1 = (const float*)d_in[2];
    const float* w2 = (const float*)d_in[3];
    const float* b2 = (const float*)d_in[4];
    float* out = (float*)d_out;

    TargetNetwork_20985210208628_kernel<<<B, 256, 0, stream>>>(x, w1, b1, w2, b2, out);
}